// Round 9
// baseline (260.655 us; speedup 1.0000x reference)
//
#include <hip/hip_runtime.h>
#include <hip/hip_bf16.h>

#define NH 16
#define HD 64
#define EMB 1024
#define BB 4
#define TT 2048
#define MTOT (BB*TT)        // 8192 rows
#define N1 (3*NH*HD)        // 3072
#define KD EMB              // 1024

// q scale: (1/sqrt(HD)) * log2(e) — softmax computed in exp2 domain
#define QSCALE 0.18033688011112042f
// fixed softmax "max" in exp2 domain (exact after 1/l normalization)
#define FMAX 14.0f

typedef __bf16 bf16x8 __attribute__((ext_vector_type(8)));
typedef __bf16 bf16x4 __attribute__((ext_vector_type(4)));
typedef float  f32x4  __attribute__((ext_vector_type(4)));
typedef __hip_bfloat16 hbf;

__device__ __forceinline__ void async_copy16(const hbf* g, hbf* l) {
    __builtin_amdgcn_global_load_lds(
        (const __attribute__((address_space(1))) void*)g,
        (__attribute__((address_space(3))) void*)l, 16, 0, 0);
}

__device__ __forceinline__ bf16x4 pack4(float x0, float x1, float x2, float x3) {
    union { bf16x4 v; hbf a[4]; } u;
    u.a[0] = __float2bfloat16(x0);
    u.a[1] = __float2bfloat16(x1);
    u.a[2] = __float2bfloat16(x2);
    u.a[3] = __float2bfloat16(x3);
    return u.v;
}

// ---------------- conversion kernels (r0-r8 proven) ----------------

__global__ __launch_bounds__(256) void f32_to_bf16_v4(const float* __restrict__ in,
                                                      hbf* __restrict__ out, int n4) {
    int i = blockIdx.x * blockDim.x + threadIdx.x;
    if (i < n4) {
        float4 v = ((const float4*)in)[i];
        *(bf16x4*)(out + 4 * (size_t)i) = pack4(v.x, v.y, v.z, v.w);
    }
}

// LDS-tiled transposing convert: out[c*R + r] = bf16(in[r*C + c]); R,C % 64 == 0
__global__ __launch_bounds__(256) void f32_to_bf16_T(const float* __restrict__ in,
                                                     hbf* __restrict__ out, int R, int C) {
    __shared__ float T[64][65];
    int bc = blockIdx.x % (C / 64), br = blockIdx.x / (C / 64);
    int r0 = br * 64, c0 = bc * 64;
    int tr = threadIdx.x >> 6, tc = threadIdx.x & 63;
    #pragma unroll
    for (int i = 0; i < 16; ++i)
        T[4 * i + tr][tc] = in[(size_t)(r0 + 4 * i + tr) * C + c0 + tc];
    __syncthreads();
    #pragma unroll
    for (int i = 0; i < 16; ++i)
        out[(size_t)(c0 + 4 * i + tr) * R + r0 + tc] = __float2bfloat16(T[tc][4 * i + tr]);
}

// ---------------- phased GEMM v3: BM=128, BN=256, BK=64, 8 waves, 4-phase ----------------
// Grids: qkv 64x12=768 (=3x256, no tail), out 64x4=256 (=1x256). LDS 96KB -> 1 block/CU.
// 8 waves 2M x 4N; per-wave C = 64x64 (4mi x 4ni). Per K-tile: 2 phases (nq=0,1),
// 16 MFMA each. Buffers: even tile -> buf0, odd -> buf1.
// Phase schedule per iteration i (t = 2i):
//   P0: LDA(b0) 8 + LDB(b0,0) 4 reads; stage B01(t+1)->b1;  BAR lgkm MM(0) BAR
//   P1: LDB(b0,1) 4 reads; stage B23(t+1)->b1 + A(t+2)->b0; BAR lgkm MM(1) vmcnt(2) BAR
//   P2: LDA(b1) 8 + LDB(b1,0) 4;   stage B01(t+2)->b0;      BAR lgkm MM(0) BAR
//   P3: LDB(b1,1) 4;               stage B23(t+2)->b0? no: B23(t+2)->b0 + A(t+3)->b1;
//                                                           BAR lgkm MM(1) vmcnt(2) BAR
// WAR: A-b0 freed after P0's closing bar (frags in regs); B-b0 after P1; A-b1 after P2;
// B-b1 after P3 (prev cycle) -> every stage sits behind the freeing barrier.
// vmcnt ledger (2 loads per stage op): enter P0 with A(t+1) in flight [2].
//   P0 +B01(t+1) ->4. P1 +B23(t+1),A(t+2) ->8; vmcnt(2) retires A(t+1)+B(t+1) (what
//   P2/P3 read), keeps A(t+2). P2 +B01(t+2) ->4. P3 +B23(t+2),A(t+3) ->8; vmcnt(2)
//   retires A(t+2)+B(t+2) (next P0 reads), keeps A(t+3). Never 0 in-loop.
// LDS swizzle (proven 0-conflict in r5): 128B rows, slot s of row r holds global
// chunk s^(r&7); reads use slot ((kk*4+g)^(c&7)). Inverse-swizzled global source.
// MODE 0: qkv scatter epilogue. MODE 1: f32 + bias.

#define GBAR  asm volatile("s_barrier" ::: "memory")
#define GLGKM { asm volatile("s_waitcnt lgkmcnt(0)" ::: "memory"); __builtin_amdgcn_sched_barrier(0); }
#define GVM2  asm volatile("s_waitcnt vmcnt(2)" ::: "memory")

template<int NBN, int MODE>
__global__ __launch_bounds__(512, 2) void gemm_v3(
    const hbf* __restrict__ A, const hbf* __restrict__ Bt,
    hbf* __restrict__ qh, hbf* __restrict__ kh, hbf* __restrict__ vt,
    const float* __restrict__ bias, float* __restrict__ out)
{
    constexpr int NKT = KD / 64;                 // 16 K-tiles
    constexpr int NIT = NKT / 2;                 // 8 iterations
    constexpr int GRID = (MTOT / 128) * NBN;
    __shared__ __align__(16) hbf As[2 * 128 * 64];   // 32 KB
    __shared__ __align__(16) hbf Bs[2 * 256 * 64];   // 64 KB

    int tid = threadIdx.x;
    int wv = tid >> 6, lane = tid & 63;
    int g = lane >> 4, c = lane & 15;
    int wm = wv >> 2, wn = wv & 3;               // 2M x 4N waves; wave C = 64x64
    int xr = c & 7;
    int wg = (blockIdx.x & 7) * (GRID / 8) + (blockIdx.x >> 3);
    int bn = wg % NBN, bm = wg / NBN;
    int m0 = bm * 128, n0 = bn * 256;

    // staging: half = 64 rows x 64 cols = 512 thr x 16B. row = tid>>3, slot = tid&7,
    // inverse-swizzled global chunk = slot ^ (row&7).
    int srow = tid >> 3;
    int sgc = (tid & 7) ^ (srow & 7);
    const hbf* pA = A  + (size_t)(m0 + srow) * KD + sgc * 8;
    const hbf* pB = Bt + (size_t)(n0 + srow) * KD + sgc * 8;
    int ldsd = (tid & ~63) * 8;

#define STG_A(t, buf)  { async_copy16(pA + (t)*64,                  As + (buf)*8192  + ldsd); \
                         async_copy16(pA + (size_t)64*KD  + (t)*64, As + (buf)*8192  + 4096 + ldsd); }
#define STG_B01(t, buf){ async_copy16(pB + (t)*64,                  Bs + (buf)*16384 + ldsd); \
                         async_copy16(pB + (size_t)64*KD  + (t)*64, Bs + (buf)*16384 + 4096 + ldsd); }
#define STG_B23(t, buf){ async_copy16(pB + (size_t)128*KD + (t)*64, Bs + (buf)*16384 + 8192 + ldsd); \
                         async_copy16(pB + (size_t)192*KD + (t)*64, Bs + (buf)*16384 + 12288 + ldsd); }

    int arow = wm * 64 + c;
    int brow = wn * 64 + c;
    bf16x8 af[4][2], bfr[2][2];
    f32x4 acc[4][4];
    #pragma unroll
    for (int i = 0; i < 4; ++i)
        #pragma unroll
        for (int j = 0; j < 4; ++j) acc[i][j] = (f32x4){0.f, 0.f, 0.f, 0.f};

#define LDA(buf) { _Pragma("unroll") for (int mi = 0; mi < 4; ++mi) { \
    const hbf* ap = As + (buf)*8192 + (arow + mi*16) * 64; \
    af[mi][0] = *(const bf16x8*)(ap + ((g ^ xr) << 3)); \
    af[mi][1] = *(const bf16x8*)(ap + (((4 + g) ^ xr) << 3)); } }
#define LDB(buf, nq) { _Pragma("unroll") for (int k2 = 0; k2 < 2; ++k2) { \
    const hbf* bp = Bs + (buf)*16384 + (brow + (nq)*32 + k2*16) * 64; \
    bfr[k2][0] = *(const bf16x8*)(bp + ((g ^ xr) << 3)); \
    bfr[k2][1] = *(const bf16x8*)(bp + (((4 + g) ^ xr) << 3)); } }
#define MM(nq) { __builtin_amdgcn_s_setprio(1); \
    _Pragma("unroll") for (int mi = 0; mi < 4; ++mi) \
      _Pragma("unroll") for (int k2 = 0; k2 < 2; ++k2) { \
        acc[mi][(nq)*2+k2] = __builtin_amdgcn_mfma_f32_16x16x32_bf16(af[mi][0], bfr[k2][0], acc[mi][(nq)*2+k2], 0, 0, 0); \
        acc[mi][(nq)*2+k2] = __builtin_amdgcn_mfma_f32_16x16x32_bf16(af[mi][1], bfr[k2][1], acc[mi][(nq)*2+k2], 0, 0, 0); } \
    __builtin_amdgcn_s_setprio(0); }

    // prologue: tile0 -> buf0 (6 halves), A(1) -> buf1. Keep A(1) in flight.
    STG_A(0, 0); STG_B01(0, 0); STG_B23(0, 0);
    STG_A(1, 1);
    GVM2;
    GBAR;
    __builtin_amdgcn_sched_barrier(0);

    for (int i = 0; i < NIT - 1; ++i) {
        int t = 2 * i;
        // P0: tile t (buf0), Q0
        LDA(0); LDB(0, 0); STG_B01(t + 1, 1);
        GBAR; GLGKM; MM(0); GBAR;
        // P1: Q1
        LDB(0, 1); STG_B23(t + 1, 1); STG_A(t + 2, 0);
        GBAR; GLGKM; MM(1);
        GVM2; GBAR;
        // P2: tile t+1 (buf1), Q0
        LDA(1); LDB(1, 0); STG_B01(t + 2, 0);
        GBAR; GLGKM; MM(0); GBAR;
        // P3: Q1
        LDB(1, 1); STG_B23(t + 2, 0); STG_A(t + 3, 1);
        GBAR; GLGKM; MM(1);
        GVM2; GBAR;
        __builtin_amdgcn_sched_barrier(0);
    }
    // peeled final iteration (t = NKT-2 in buf0, NKT-1 in buf1)
    {
        LDA(0); LDB(0, 0); STG_B01(NKT - 1, 1);
        GBAR; GLGKM; MM(0); GBAR;
        LDB(0, 1); STG_B23(NKT - 1, 1);
        GBAR; GLGKM; MM(1);
        asm volatile("s_waitcnt vmcnt(0)" ::: "memory");
        GBAR;
        LDA(1); LDB(1, 0);
        GBAR; GLGKM; MM(0); GBAR;
        LDB(1, 1);
        GBAR; GLGKM; MM(1);
    }
#undef STG_A
#undef STG_B01
#undef STG_B23
#undef LDA
#undef LDB
#undef MM

    if constexpr (MODE == 0) {
        int colbase = n0 + wn * 64;                  // one full head per wave
        int which = colbase >> 10;                   // 0:q 1:k 2:v
        int h = (colbase & 1023) >> 6;
        int b = m0 / TT;
        int trow = (m0 % TT) + wm * 64;
        if (which < 2) {
            float scale = (which == 0) ? QSCALE : 1.0f;
            hbf* dst = ((which == 0) ? qh : kh) + ((size_t)b * NH + h) * TT * HD;
            #pragma unroll
            for (int mi = 0; mi < 4; ++mi)
                #pragma unroll
                for (int nj = 0; nj < 4; ++nj) {
                    int d = nj * 16 + c;
                    #pragma unroll
                    for (int r = 0; r < 4; ++r) {
                        int trw = trow + mi * 16 + g * 4 + r;
                        dst[(size_t)trw * HD + d] = __float2bfloat16(acc[mi][nj][r] * scale);
                    }
                }
        } else {
            hbf* dst = vt + ((size_t)b * NH + h) * TT * HD;   // [HD][TT] per head
            #pragma unroll
            for (int mi = 0; mi < 4; ++mi)
                #pragma unroll
                for (int nj = 0; nj < 4; ++nj) {
                    int d = nj * 16 + c;
                    #pragma unroll
                    for (int r = 0; r < 4; ++r) {
                        int trw = trow + mi * 16 + g * 4 + r;
                        dst[(size_t)d * TT + trw] = __float2bfloat16(acc[mi][nj][r]);
                    }
                }
        }
    } else {
        #pragma unroll
        for (int mi = 0; mi < 4; ++mi)
            #pragma unroll
            for (int nj = 0; nj < 4; ++nj) {
                int col = n0 + wn * 64 + nj * 16 + c;
                float bv = bias[col];
                #pragma unroll
                for (int r = 0; r < 4; ++r) {
                    int row = m0 + wm * 64 + mi * 16 + g * 4 + r;
                    out[(size_t)row * EMB + col] = acc[mi][nj][r] + bv;
                }
            }
    }
}

// ---------------- flash attention v7 (r8-verified): dbuf 128-key stages ----------------
// Block = 512 thr = 8 waves, supertile pair (pi, 15-pi), 128-key K/V stages.
// K/V LDS double-buffered (80 KB total -> 2 blocks/CU).
// Per stage: compute buf[s&1] -> barrier -> refill buf[s&1] with stage s+2 ->
// counted vmcnt(4) (never 0 in-loop) -> barrier.
// Fixed-max softmax in exp2 domain; l via ones-MFMA. XCD-major bh map (FETCH 24.6MB).

__global__ __launch_bounds__(512, 4) void attn(
    const hbf* __restrict__ qh, const hbf* __restrict__ kh, const hbf* __restrict__ vt,
    hbf* __restrict__ y)
{
    __shared__ __align__(16) hbf Ks[2 * 128 * 64];   // 32 KB [key][dim-swz] dbuf
    __shared__ __align__(16) hbf Vs[2 * 64 * 128];   // 32 KB [dim][key-swz] dbuf
    __shared__ __align__(16) hbf Ps[8][16 * 64];     // 16 KB per-wave P^T

    int tid = threadIdx.x;
    int wv = tid >> 6, lane = tid & 63;
    int g = lane >> 4, c = lane & 15;
    int c7 = c & 7;

    int bidx = blockIdx.x;
    int bh = (bidx & 7) | (((bidx >> 6) & 7) << 3);
    int pi = (bidx >> 3) & 7;
    int b = bh >> 4, h = bh & 15;

    const hbf* Q = qh + (size_t)bh * TT * HD;
    const hbf* K = kh + (size_t)bh * TT * HD;
    const hbf* V = vt + (size_t)bh * TT * HD;   // [HD][TT]
    hbf* Pq = &Ps[wv][0];

#define ASTG(ss, buf) { \
    int k0s = (ss) * 128; \
    _Pragma("unroll") for (int it = 0; it < 2; ++it) { \
        int e = it * 4096 + tid * 8; \
        int key = e >> 6, sblk = (e >> 3) & 7; \
        int dblk = sblk ^ (key & 7); \
        async_copy16(K + (size_t)(k0s + key) * HD + dblk * 8, \
                     Ks + (buf) * 8192 + it * 4096 + (tid & ~63) * 8); } \
    _Pragma("unroll") for (int it = 0; it < 2; ++it) { \
        int e = it * 4096 + tid * 8; \
        int dim = e >> 7, kb = (e >> 3) & 15; \
        int skb = kb ^ (dim & 7); \
        async_copy16(V + (size_t)dim * TT + k0s + skb * 8, \
                     Vs + (buf) * 8192 + it * 4096 + (tid & ~63) * 8); } }

    union { bf16x8 v; hbf a[8]; } uo;
    #pragma unroll
    for (int i = 0; i < 8; ++i) uo.a[i] = __float2bfloat16(1.0f);
    const bf16x8 ones8 = uo.v;

    #pragma unroll
    for (int pass = 0; pass < 2; ++pass) {
        int sst = pass ? (15 - pi) : pi;
        int qb = sst * 128;
        int q0 = qb + wv * 16;
        int kend = q0 + 16;
        int S = sst + 1;                         // 128-key stages this pass

        bf16x8 aq0 = *(const bf16x8*)(Q + (size_t)(q0 + c) * HD + g * 8);
        bf16x8 aq1 = *(const bf16x8*)(Q + (size_t)(q0 + c) * HD + 32 + g * 8);

        f32x4 lacc = (f32x4){0.f, 0.f, 0.f, 0.f};
        f32x4 o[4];
        #pragma unroll
        for (int d = 0; d < 4; ++d) o[d] = (f32x4){0.f, 0.f, 0.f, 0.f};

        // prologue: stage 0 (and 1) — only stage 0 must land before compute
        ASTG(0, 0);
        if (S > 1) {
            ASTG(1, 1);
            asm volatile("s_waitcnt vmcnt(4)" ::: "memory");
        } else {
            asm volatile("s_waitcnt vmcnt(0)" ::: "memory");
        }
        asm volatile("s_barrier" ::: "memory");
        __builtin_amdgcn_sched_barrier(0);

        for (int s = 0; s < S; ++s) {
            int k0 = s * 128;
            const hbf* Kb = Ks + (s & 1) * 8192;
            const hbf* Vb = Vs + (s & 1) * 8192;

            #pragma unroll
            for (int ch = 0; ch < 2; ++ch) {
                int c64 = k0 + ch * 64;
                if (c64 < kend) {                         // wave-uniform
                    f32x4 sv[4];
                    #pragma unroll
                    for (int t = 0; t < 4; ++t) {
                        int kt = c64 + 16 * t;
                        if (kt < kend) {                  // wave-uniform
                            int rb = (ch * 64 + 16 * t + c) * 64;
                            bf16x8 kf0 = *(const bf16x8*)(Kb + rb + ((g ^ c7) << 3));
                            bf16x8 kf1 = *(const bf16x8*)(Kb + rb + (((4 + g) ^ c7) << 3));
                            f32x4 a = (f32x4){-FMAX, -FMAX, -FMAX, -FMAX};
                            a = __builtin_amdgcn_mfma_f32_16x16x32_bf16(kf0, aq0, a, 0, 0, 0);
                            a = __builtin_amdgcn_mfma_f32_16x16x32_bf16(kf1, aq1, a, 0, 0, 0);
                            if (kt == q0) {               // diagonal: key<=q ⇔ g*4+r<=c
                                #pragma unroll
                                for (int r = 0; r < 4; ++r)
                                    a[r] = (g * 4 + r <= c) ? a[r] : -1e30f;
                            }
                            sv[t] = a;
                        } else
                            sv[t] = (f32x4){-1e30f, -1e30f, -1e30f, -1e30f};
                    }
                    #pragma unroll
                    for (int t = 0; t < 4; ++t) {
                        f32x4 e;
                        #pragma unroll
                        for (int r = 0; r < 4; ++r) e[r] = __builtin_amdgcn_exp2f(sv[t][r]);
                        *(bf16x4*)(Pq + c * 64 + (((2 * t + (g >> 1)) ^ c7) << 3) + ((g & 1) << 2)) =
                            pack4(e[0], e[1], e[2], e[3]);
                    }
                    #pragma unroll
                    for (int sc = 0; sc < 2; ++sc) {
                        if (c64 + 32 * sc < kend) {       // wave-uniform
                            bf16x8 pf = *(const bf16x8*)(Pq + c * 64 + (((4 * sc + g) ^ c7) << 3));
                            lacc = __builtin_amdgcn_mfma_f32_16x16x32_bf16(ones8, pf, lacc, 0, 0, 0);
                            #pragma unroll
                            for (int d = 0; d < 4; ++d) {
                                int dim = d * 16 + c;
                                bf16x8 vf = *(const bf16x8*)(Vb + dim * 128 +
                                              (((ch * 8 + 4 * sc + g) ^ c7) << 3));
                                o[d] = __builtin_amdgcn_mfma_f32_16x16x32_bf16(vf, pf, o[d], 0, 0, 0);
                            }
                        }
                    }
                }
            }

            asm volatile("s_barrier" ::: "memory");       // all waves done with buf[s&1]
            __builtin_amdgcn_sched_barrier(0);
            if (s + 2 < S) {
                ASTG(s + 2, s & 1);                       // refill freed buffer
                asm volatile("s_waitcnt vmcnt(4)" ::: "memory");   // stage s+1 landed
            } else if (s + 1 < S) {
                asm volatile("s_waitcnt vmcnt(0)" ::: "memory");   // last refill landed
            }
            asm volatile("s_barrier" ::: "memory");       // buf[(s+1)&1] ready for all
            __builtin_amdgcn_sched_barrier(0);
        }

        float inv = 1.0f / lacc[0];
        #pragma unroll
        for (int d = 0; d < 4; ++d) {
            *(bf16x4*)(y + (size_t)(b * TT + q0 + c) * EMB + h * HD + d * 16 + g * 4) =
                pack4(o[d][0] * inv, o[d][1] * inv, o[d][2] * inv, o[d][3] * inv);
        }
    }
#undef ASTG
}

// ---------------- launch ----------------

extern "C" void kernel_launch(void* const* d_in, const int* in_sizes, int n_in,
                              void* d_out, int out_size, void* d_ws, size_t ws_size,
                              hipStream_t stream)
{
    const float* x      = (const float*)d_in[0];
    const float* W_attn = (const float*)d_in[1];
    const float* W_proj = (const float*)d_in[2];
    const float* b_proj = (const float*)d_in[3];
    float* out = (float*)d_out;

    char* ws = (char*)d_ws;
    hbf* xb    = (hbf*)ws; ws += (size_t)MTOT * KD * 2;
    hbf* wab_t = (hbf*)ws; ws += (size_t)N1 * KD * 2;
    hbf* wpb_t = (hbf*)ws; ws += (size_t)EMB * EMB * 2;
    hbf* qh    = (hbf*)ws; ws += (size_t)MTOT * EMB * 2;
    hbf* kh    = (hbf*)ws; ws += (size_t)MTOT * EMB * 2;
    hbf* vt    = (hbf*)ws; ws += (size_t)MTOT * EMB * 2;
    hbf* yb    = (hbf*)ws; ws += (size_t)MTOT * EMB * 2;

    f32_to_bf16_v4<<<(MTOT * KD / 4 + 255) / 256, 256, 0, stream>>>(x, xb, MTOT * KD / 4);
    f32_to_bf16_T<<<(KD / 64) * (N1 / 64), 256, 0, stream>>>(W_attn, wab_t, KD, N1);
    f32_to_bf16_T<<<(KD / 64) * (EMB / 64), 256, 0, stream>>>(W_proj, wpb_t, KD, EMB);

    gemm_v3<N1 / 256, 0><<<(MTOT / 128) * (N1 / 256), 512, 0, stream>>>(
        xb, wab_t, qh, kh, vt, nullptr, nullptr);
    attn<<<BB * NH * 8, 512, 0, stream>>>(qh, kh, vt, yb);
    gemm_v3<EMB / 256, 1><<<(MTOT / 128) * (EMB / 256), 512, 0, stream>>>(
        yb, wpb_t, nullptr, nullptr, nullptr, b_proj, out);
}

// Round 13
// 250.202 us; speedup vs baseline: 1.0418x; 1.0418x over previous
//
#include <hip/hip_runtime.h>
#include <hip/hip_bf16.h>

#define NH 16
#define HD 64
#define EMB 1024
#define BB 4
#define TT 2048
#define MTOT (BB*TT)        // 8192 rows
#define N1 (3*NH*HD)        // 3072
#define KD EMB              // 1024

// q scale: (1/sqrt(HD)) * log2(e) — softmax computed in exp2 domain
#define QSCALE 0.18033688011112042f
// fixed softmax "max" in exp2 domain (exact after 1/l normalization)
#define FMAX 14.0f

typedef __bf16 bf16x8 __attribute__((ext_vector_type(8)));
typedef __bf16 bf16x4 __attribute__((ext_vector_type(4)));
typedef float  f32x4  __attribute__((ext_vector_type(4)));
typedef __hip_bfloat16 hbf;

__device__ __forceinline__ void async_copy16(const hbf* g, hbf* l) {
    __builtin_amdgcn_global_load_lds(
        (const __attribute__((address_space(1))) void*)g,
        (__attribute__((address_space(3))) void*)l, 16, 0, 0);
}

__device__ __forceinline__ bf16x4 pack4(float x0, float x1, float x2, float x3) {
    union { bf16x4 v; hbf a[4]; } u;
    u.a[0] = __float2bfloat16(x0);
    u.a[1] = __float2bfloat16(x1);
    u.a[2] = __float2bfloat16(x2);
    u.a[3] = __float2bfloat16(x3);
    return u.v;
}

// ---------------- conversion kernels (r0-r9 proven) ----------------

__global__ __launch_bounds__(256) void f32_to_bf16_v4(const float* __restrict__ in,
                                                      hbf* __restrict__ out, int n4) {
    int i = blockIdx.x * blockDim.x + threadIdx.x;
    if (i < n4) {
        float4 v = ((const float4*)in)[i];
        *(bf16x4*)(out + 4 * (size_t)i) = pack4(v.x, v.y, v.z, v.w);
    }
}

// LDS-tiled transposing convert: out[c*R + r] = bf16(in[r*C + c]); R,C % 64 == 0
__global__ __launch_bounds__(256) void f32_to_bf16_T(const float* __restrict__ in,
                                                     hbf* __restrict__ out, int R, int C) {
    __shared__ float T[64][65];
    int bc = blockIdx.x % (C / 64), br = blockIdx.x / (C / 64);
    int r0 = br * 64, c0 = bc * 64;
    int tr = threadIdx.x >> 6, tc = threadIdx.x & 63;
    #pragma unroll
    for (int i = 0; i < 16; ++i)
        T[4 * i + tr][tc] = in[(size_t)(r0 + 4 * i + tr) * C + c0 + tc];
    __syncthreads();
    #pragma unroll
    for (int i = 0; i < 16; ++i)
        out[(size_t)(c0 + 4 * i + tr) * R + r0 + tc] = __float2bfloat16(T[tc][4 * i + tr]);
}

// ---------------- GEMM v2c: r8's gemm_v2 + conflict-free swizzle ----------------
// 256 thr = 4 waves (2x2), block 128x128, BK=32, LDS 32KB dbuf -> 4 blocks/CU.
// Stage t+2 into just-freed buffer behind lgkmcnt(0)+barrier; one counted
// vmcnt(4) per tile (never 0 in-loop).  (r8-verified structure.)
// SWIZZLE FIX vs r8: slot = chunk ^ ((row>>1)&3)  [was ^(row&3)].
// Derivation: 64B rows = 16 banks; a b128 phase's 16 lanes map to bank-group
// 16*(c&1) + 4*slot. With ^(row&3), even-c lanes only realize slots {g, g^2}
// (4-way conflict -> r8 measured 6.29M). With ^((row>>1)&3), (c>>1)&3 cycles
// {0,1,2,3} twice -> 2 lanes/group = free 2-way (m136). Involution holds:
// LDS[r][s] = G[r][s^f(r)], read slot g^f(r) -> chunk g; f(r)=(r>>1)&3 and
// all row offsets are multiples of 16 so f(row) = (c>>1)&3 at read time.
// MODE 0: qkv scatter epilogue. MODE 1: f32 + bias.

template<int NBN, int MODE>
__global__ __launch_bounds__(256, 4) void gemm_v2(
    const hbf* __restrict__ A, const hbf* __restrict__ Bt,
    hbf* __restrict__ qh, hbf* __restrict__ kh, hbf* __restrict__ vt,
    const float* __restrict__ bias, float* __restrict__ out)
{
    constexpr int NKT = KD / 32;                 // 32 K-tiles
    __shared__ __align__(16) hbf As[2 * 128 * 32];   // 16 KB
    __shared__ __align__(16) hbf Bs[2 * 128 * 32];   // 16 KB

    int tid = threadIdx.x;
    int wv = tid >> 6, lane = tid & 63;
    int g = lane >> 4, c = lane & 15;
    int wm = wv >> 1, wn = wv & 1;               // 2x2 waves; wave out = 64x64
    int wg = (blockIdx.x & 7) * (8 * NBN) + (blockIdx.x >> 3);
    int bn = wg % NBN, bm = wg / NBN;
    int m0 = bm * 128, n0 = bn * 128;

    int sr = tid >> 2;
    int sgc = (tid & 3) ^ ((sr >> 1) & 3);       // inverse-swizzled global chunk
    const hbf* Asrc0 = A  + (size_t)(m0 + sr) * KD + sgc * 8;
    const hbf* Asrc1 = A  + (size_t)(m0 + 64 + sr) * KD + sgc * 8;
    const hbf* Bsrc0 = Bt + (size_t)(n0 + sr) * KD + sgc * 8;
    const hbf* Bsrc1 = Bt + (size_t)(n0 + 64 + sr) * KD + sgc * 8;
    int ld0 = (tid & ~63) * 8, ld1 = 2048 + (tid & ~63) * 8;

#define STG(tt, buf) { \
    async_copy16(Asrc0 + (tt) * 32, As + (buf) * 4096 + ld0); \
    async_copy16(Asrc1 + (tt) * 32, As + (buf) * 4096 + ld1); \
    async_copy16(Bsrc0 + (tt) * 32, Bs + (buf) * 4096 + ld0); \
    async_copy16(Bsrc1 + (tt) * 32, Bs + (buf) * 4096 + ld1); }

    int x3 = (c >> 1) & 3;                       // f(row) at read time
    int ao = (wm * 64 + c) * 32 + ((g ^ x3) << 3);
    int bo = (wn * 64 + c) * 32 + ((g ^ x3) << 3);

    f32x4 acc[4][4];
    #pragma unroll
    for (int i = 0; i < 4; ++i)
        #pragma unroll
        for (int j = 0; j < 4; ++j) acc[i][j] = (f32x4){0.f, 0.f, 0.f, 0.f};

    STG(0, 0);
    STG(1, 1);
    asm volatile("s_waitcnt vmcnt(4)" ::: "memory");
    asm volatile("s_barrier" ::: "memory");
    __builtin_amdgcn_sched_barrier(0);

    for (int t = 0; t < NKT; ++t) {
        int cur = t & 1;
        const hbf* Ab = As + cur * 4096;
        const hbf* Bb = Bs + cur * 4096;
        bf16x8 af[4], bfr[4];
        #pragma unroll
        for (int i = 0; i < 4; ++i) af[i] = *(const bf16x8*)(Ab + ao + i * 512);
        #pragma unroll
        for (int j = 0; j < 4; ++j) bfr[j] = *(const bf16x8*)(Bb + bo + j * 512);
        asm volatile("s_waitcnt lgkmcnt(0)" ::: "memory");
        __builtin_amdgcn_sched_barrier(0);
        asm volatile("s_barrier" ::: "memory");
        __builtin_amdgcn_sched_barrier(0);
        if (t + 2 < NKT) STG(t + 2, cur);
        __builtin_amdgcn_s_setprio(1);
        #pragma unroll
        for (int i = 0; i < 4; ++i)
            #pragma unroll
            for (int j = 0; j < 4; ++j)
                acc[i][j] = __builtin_amdgcn_mfma_f32_16x16x32_bf16(af[i], bfr[j], acc[i][j], 0, 0, 0);
        __builtin_amdgcn_s_setprio(0);
        if (t + 2 < NKT) { asm volatile("s_waitcnt vmcnt(4)" ::: "memory"); }
        else             { asm volatile("s_waitcnt vmcnt(0)" ::: "memory"); }
        asm volatile("s_barrier" ::: "memory");
        __builtin_amdgcn_sched_barrier(0);
    }
#undef STG

    if constexpr (MODE == 0) {
        int colbase = n0 + wn * 64;
        int which = colbase >> 10;
        int h = (colbase & 1023) >> 6;
        int b = m0 / TT;
        int trow = (m0 % TT) + wm * 64;
        if (which < 2) {
            float scale = (which == 0) ? QSCALE : 1.0f;
            hbf* dst = ((which == 0) ? qh : kh) + ((size_t)b * NH + h) * TT * HD;
            #pragma unroll
            for (int i = 0; i < 4; ++i)
                #pragma unroll
                for (int j = 0; j < 4; ++j) {
                    int d = j * 16 + c;
                    #pragma unroll
                    for (int r = 0; r < 4; ++r) {
                        int trw = trow + i * 16 + g * 4 + r;
                        dst[(size_t)trw * HD + d] = __float2bfloat16(acc[i][j][r] * scale);
                    }
                }
        } else {
            hbf* dst = vt + ((size_t)b * NH + h) * TT * HD;   // [HD][TT] per head
            #pragma unroll
            for (int i = 0; i < 4; ++i)
                #pragma unroll
                for (int j = 0; j < 4; ++j) {
                    int d = j * 16 + c;
                    #pragma unroll
                    for (int r = 0; r < 4; ++r) {
                        int trw = trow + i * 16 + g * 4 + r;
                        dst[(size_t)d * TT + trw] = __float2bfloat16(acc[i][j][r]);
                    }
                }
        }
    } else {
        #pragma unroll
        for (int i = 0; i < 4; ++i)
            #pragma unroll
            for (int j = 0; j < 4; ++j) {
                int col = n0 + wn * 64 + j * 16 + c;
                float bv = bias[col];
                #pragma unroll
                for (int r = 0; r < 4; ++r) {
                    int row = m0 + wm * 64 + i * 16 + g * 4 + r;
                    out[(size_t)row * EMB + col] = acc[i][j][r] + bv;
                }
            }
    }
}

// ---------------- flash attention v7 (r8-verified): dbuf 128-key stages ----------------
// Block = 512 thr = 8 waves, supertile pair (pi, 15-pi), 128-key K/V stages.
// K/V LDS double-buffered (80 KB total -> 2 blocks/CU).
// Per stage: compute buf[s&1] -> barrier -> refill buf[s&1] with stage s+2 ->
// counted vmcnt(4) (never 0 in-loop) -> barrier.
// Fixed-max softmax in exp2 domain; l via ones-MFMA. XCD-major bh map (FETCH 24.6MB).

__global__ __launch_bounds__(512, 4) void attn(
    const hbf* __restrict__ qh, const hbf* __restrict__ kh, const hbf* __restrict__ vt,
    hbf* __restrict__ y)
{
    __shared__ __align__(16) hbf Ks[2 * 128 * 64];   // 32 KB [key][dim-swz] dbuf
    __shared__ __align__(16) hbf Vs[2 * 64 * 128];   // 32 KB [dim][key-swz] dbuf
    __shared__ __align__(16) hbf Ps[8][16 * 64];     // 16 KB per-wave P^T

    int tid = threadIdx.x;
    int wv = tid >> 6, lane = tid & 63;
    int g = lane >> 4, c = lane & 15;
    int c7 = c & 7;

    int bidx = blockIdx.x;
    int bh = (bidx & 7) | (((bidx >> 6) & 7) << 3);
    int pi = (bidx >> 3) & 7;
    int b = bh >> 4, h = bh & 15;

    const hbf* Q = qh + (size_t)bh * TT * HD;
    const hbf* K = kh + (size_t)bh * TT * HD;
    const hbf* V = vt + (size_t)bh * TT * HD;   // [HD][TT]
    hbf* Pq = &Ps[wv][0];

#define ASTG(ss, buf) { \
    int k0s = (ss) * 128; \
    _Pragma("unroll") for (int it = 0; it < 2; ++it) { \
        int e = it * 4096 + tid * 8; \
        int key = e >> 6, sblk = (e >> 3) & 7; \
        int dblk = sblk ^ (key & 7); \
        async_copy16(K + (size_t)(k0s + key) * HD + dblk * 8, \
                     Ks + (buf) * 8192 + it * 4096 + (tid & ~63) * 8); } \
    _Pragma("unroll") for (int it = 0; it < 2; ++it) { \
        int e = it * 4096 + tid * 8; \
        int dim = e >> 7, kb = (e >> 3) & 15; \
        int skb = kb ^ (dim & 7); \
        async_copy16(V + (size_t)dim * TT + k0s + skb * 8, \
                     Vs + (buf) * 8192 + it * 4096 + (tid & ~63) * 8); } }

    union { bf16x8 v; hbf a[8]; } uo;
    #pragma unroll
    for (int i = 0; i < 8; ++i) uo.a[i] = __float2bfloat16(1.0f);
    const bf16x8 ones8 = uo.v;

    #pragma unroll
    for (int pass = 0; pass < 2; ++pass) {
        int sst = pass ? (15 - pi) : pi;
        int qb = sst * 128;
        int q0 = qb + wv * 16;
        int kend = q0 + 16;
        int S = sst + 1;                         // 128-key stages this pass

        bf16x8 aq0 = *(const bf16x8*)(Q + (size_t)(q0 + c) * HD + g * 8);
        bf16x8 aq1 = *(const bf16x8*)(Q + (size_t)(q0 + c) * HD + 32 + g * 8);

        f32x4 lacc = (f32x4){0.f, 0.f, 0.f, 0.f};
        f32x4 o[4];
        #pragma unroll
        for (int d = 0; d < 4; ++d) o[d] = (f32x4){0.f, 0.f, 0.f, 0.f};

        // prologue: stage 0 (and 1) — only stage 0 must land before compute
        ASTG(0, 0);
        if (S > 1) {
            ASTG(1, 1);
            asm volatile("s_waitcnt vmcnt(4)" ::: "memory");
        } else {
            asm volatile("s_waitcnt vmcnt(0)" ::: "memory");
        }
        asm volatile("s_barrier" ::: "memory");
        __builtin_amdgcn_sched_barrier(0);

        for (int s = 0; s < S; ++s) {
            int k0 = s * 128;
            const hbf* Kb = Ks + (s & 1) * 8192;
            const hbf* Vb = Vs + (s & 1) * 8192;

            #pragma unroll
            for (int ch = 0; ch < 2; ++ch) {
                int c64 = k0 + ch * 64;
                if (c64 < kend) {                         // wave-uniform
                    f32x4 sv[4];
                    #pragma unroll
                    for (int t = 0; t < 4; ++t) {
                        int kt = c64 + 16 * t;
                        if (kt < kend) {                  // wave-uniform
                            int rb = (ch * 64 + 16 * t + c) * 64;
                            bf16x8 kf0 = *(const bf16x8*)(Kb + rb + ((g ^ c7) << 3));
                            bf16x8 kf1 = *(const bf16x8*)(Kb + rb + (((4 + g) ^ c7) << 3));
                            f32x4 a = (f32x4){-FMAX, -FMAX, -FMAX, -FMAX};
                            a = __builtin_amdgcn_mfma_f32_16x16x32_bf16(kf0, aq0, a, 0, 0, 0);
                            a = __builtin_amdgcn_mfma_f32_16x16x32_bf16(kf1, aq1, a, 0, 0, 0);
                            if (kt == q0) {               // diagonal: key<=q ⇔ g*4+r<=c
                                #pragma unroll
                                for (int r = 0; r < 4; ++r)
                                    a[r] = (g * 4 + r <= c) ? a[r] : -1e30f;
                            }
                            sv[t] = a;
                        } else
                            sv[t] = (f32x4){-1e30f, -1e30f, -1e30f, -1e30f};
                    }
                    #pragma unroll
                    for (int t = 0; t < 4; ++t) {
                        f32x4 e;
                        #pragma unroll
                        for (int r = 0; r < 4; ++r) e[r] = __builtin_amdgcn_exp2f(sv[t][r]);
                        *(bf16x4*)(Pq + c * 64 + (((2 * t + (g >> 1)) ^ c7) << 3) + ((g & 1) << 2)) =
                            pack4(e[0], e[1], e[2], e[3]);
                    }
                    #pragma unroll
                    for (int sc = 0; sc < 2; ++sc) {
                        if (c64 + 32 * sc < kend) {       // wave-uniform
                            bf16x8 pf = *(const bf16x8*)(Pq + c * 64 + (((4 * sc + g) ^ c7) << 3));
                            lacc = __builtin_amdgcn_mfma_f32_16x16x32_bf16(ones8, pf, lacc, 0, 0, 0);
                            #pragma unroll
                            for (int d = 0; d < 4; ++d) {
                                int dim = d * 16 + c;
                                bf16x8 vf = *(const bf16x8*)(Vb + dim * 128 +
                                              (((ch * 8 + 4 * sc + g) ^ c7) << 3));
                                o[d] = __builtin_amdgcn_mfma_f32_16x16x32_bf16(vf, pf, o[d], 0, 0, 0);
                            }
                        }
                    }
                }
            }

            asm volatile("s_barrier" ::: "memory");       // all waves done with buf[s&1]
            __builtin_amdgcn_sched_barrier(0);
            if (s + 2 < S) {
                ASTG(s + 2, s & 1);                       // refill freed buffer
                asm volatile("s_waitcnt vmcnt(4)" ::: "memory");   // stage s+1 landed
            } else if (s + 1 < S) {
                asm volatile("s_waitcnt vmcnt(0)" ::: "memory");   // last refill landed
            }
            asm volatile("s_barrier" ::: "memory");       // buf[(s+1)&1] ready for all
            __builtin_amdgcn_sched_barrier(0);
        }

        float inv = 1.0f / lacc[0];
        #pragma unroll
        for (int d = 0; d < 4; ++d) {
            *(bf16x4*)(y + (size_t)(b * TT + q0 + c) * EMB + h * HD + d * 16 + g * 4) =
                pack4(o[d][0] * inv, o[d][1] * inv, o[d][2] * inv, o[d][3] * inv);
        }
    }
#undef ASTG
}

// ---------------- launch ----------------

extern "C" void kernel_launch(void* const* d_in, const int* in_sizes, int n_in,
                              void* d_out, int out_size, void* d_ws, size_t ws_size,
                              hipStream_t stream)
{
    const float* x      = (const float*)d_in[0];
    const float* W_attn = (const float*)d_in[1];
    const float* W_proj = (const float*)d_in[2];
    const float* b_proj = (const float*)d_in[3];
    float* out = (float*)d_out;

    char* ws = (char*)d_ws;
    hbf* xb    = (hbf*)ws; ws += (size_t)MTOT * KD * 2;
    hbf* wab_t = (hbf*)ws; ws += (size_t)N1 * KD * 2;
    hbf* wpb_t = (hbf*)ws; ws += (size_t)EMB * EMB * 2;
    hbf* qh    = (hbf*)ws; ws += (size_t)MTOT * EMB * 2;
    hbf* kh    = (hbf*)ws; ws += (size_t)MTOT * EMB * 2;
    hbf* vt    = (hbf*)ws; ws += (size_t)MTOT * EMB * 2;
    hbf* yb    = (hbf*)ws; ws += (size_t)MTOT * EMB * 2;

    f32_to_bf16_v4<<<(MTOT * KD / 4 + 255) / 256, 256, 0, stream>>>(x, xb, MTOT * KD / 4);
    f32_to_bf16_T<<<(KD / 64) * (N1 / 64), 256, 0, stream>>>(W_attn, wab_t, KD, N1);
    f32_to_bf16_T<<<(KD / 64) * (EMB / 64), 256, 0, stream>>>(W_proj, wpb_t, KD, EMB);

    gemm_v2<N1 / 128, 0><<<(MTOT / 128) * (N1 / 128), 256, 0, stream>>>(
        xb, wab_t, qh, kh, vt, nullptr, nullptr);
    attn<<<BB * NH * 8, 512, 0, stream>>>(qh, kh, vt, yb);
    gemm_v2<EMB / 128, 1><<<(MTOT / 128) * (EMB / 128), 256, 0, stream>>>(
        yb, wpb_t, nullptr, nullptr, nullptr, b_proj, out);
}